// Round 15
// baseline (214.905 us; speedup 1.0000x reference)
//
#include <hip/hip_runtime.h>
#include <hip/hip_bf16.h>

// x: [32, 2048, 17, 3] -> [65536, 51]
// u: panel-major packed bf16: u5[nb(0..5)][m>>2][c(0..127)][m&3], nb=col>>7
//    (PRE-activation f/r).  y: [65536, 51]
static constexpr int M_ROWS = 32 * 2048;   // 65536
static constexpr int MG     = M_ROWS / 4;  // 16384 m-groups
static constexpr int TC     = 64;          // scan chunk length
static constexpr int NCHUNK = 2048 / TC;   // 32

typedef __attribute__((ext_vector_type(8))) __bf16 bf16x8;
typedef __attribute__((ext_vector_type(4))) __bf16 bf16x4;
typedef __attribute__((ext_vector_type(4))) float  f32x4;

#define VM_WAIT(N) asm volatile("s_waitcnt vmcnt(" #N ")" ::: "memory")
#define LGKM_WAIT0 asm volatile("s_waitcnt lgkmcnt(0)" ::: "memory")

__device__ __forceinline__ void async_copy16(void* lds_ptr, const void* g_ptr) {
  __builtin_amdgcn_global_load_lds(
      (const __attribute__((address_space(1))) void*)g_ptr,
      (__attribute__((address_space(3))) void*)lds_ptr, 16, 0, 0);
}

__device__ __forceinline__ float sigmoid_f(float v) {
  return 1.f / (1.f + __expf(-v));
}
__device__ __forceinline__ float tanh_f(float v) {
  v = fminf(fmaxf(v, -15.f), 15.f);
  float e = __expf(-2.f * v);
  return (1.f - e) / (1.f + e);
}

// -------------------------------------------------------------------------
// Prep: W_l [2][256][768] f32 -> Wt [2][768][256] bf16 (transposed)
//       W_out [256][51] f32 -> WtO [128][256] bf16 (transposed, padded)
//       Wc = W_in @ W_l[0]  [51][768] f32-accum -> WcT [768][64] bf16
//       bc[o] = sum_j b_in[j]*W0[j][o] + b_l0[o]   (f32)
// -------------------------------------------------------------------------
__global__ __launch_bounds__(256) void prep_weights(
    const float* __restrict__ Wl, const float* __restrict__ Wout,
    const float* __restrict__ Win, const float* __restrict__ b_in,
    const float* __restrict__ b_l,
    __hip_bfloat16* __restrict__ Wt, __hip_bfloat16* __restrict__ WtO,
    __hip_bfloat16* __restrict__ WcT, float* __restrict__ bc)
{
  const int idx = blockIdx.x * 256 + threadIdx.x;
  const int T1 = 2 * 768 * 256;          // 393216
  const int T2 = T1 + 128 * 256;         // 425984
  const int T4 = T2 + 768 * 64;          // 475136
  const int T5 = T4 + 768;               // 475904
  if (idx < T1) {
    int l = idx / (768 * 256);
    int rem = idx - l * 768 * 256;
    int n = rem >> 8;
    int k = rem & 255;
    Wt[idx] = __float2bfloat16(Wl[(size_t)l * 196608 + (size_t)k * 768 + n]);
  } else if (idx < T2) {
    int i2 = idx - T1;
    int n = i2 >> 8, k = i2 & 255;
    float v = (n < 51) ? Wout[(size_t)k * 51 + n] : 0.f;
    WtO[i2] = __float2bfloat16(v);
  } else if (idx < T4) {
    int i4 = idx - T2;
    int o = i4 >> 6, k = i4 & 63;        // o: 0..767, k: 0..63
    float acc = 0.f;
    if (k < 51) {
      const float* wi = Win + (size_t)k * 256;   // row k of W_in, contiguous
      for (int j = 0; j < 256; ++j)
        acc += wi[j] * Wl[(size_t)j * 768 + o];  // W0 = W_l[0]
    }
    WcT[i4] = __float2bfloat16(acc);
  } else if (idx < T5) {
    int o = idx - T4;
    float acc = b_l[o];                  // b_l0
    for (int j = 0; j < 256; ++j)
      acc += b_in[j] * Wl[(size_t)j * 768 + o];
    bc[o] = acc;
  }
}

// -------------------------------------------------------------------------
// cast/pad x [65536][51] f32 -> xb [65536][64] bf16
// -------------------------------------------------------------------------
__global__ __launch_bounds__(256) void cast_x(
    const float* __restrict__ x, __hip_bfloat16* __restrict__ xb)
{
  const int t = blockIdx.x * 256 + threadIdx.x;  // 524288 = 65536 * 8
  const int row = t >> 3, cg = t & 7;
  __hip_bfloat16 tmp[8];
#pragma unroll
  for (int i = 0; i < 8; ++i) {
    int c = cg * 8 + i;
    float v = (c < 51) ? x[(size_t)row * 51 + c] : 0.f;
    tmp[i] = __float2bfloat16(v);
  }
  *reinterpret_cast<int4*>(&xb[(size_t)row * 64 + cg * 8]) =
      *reinterpret_cast<const int4*>(tmp);
}

// -------------------------------------------------------------------------
// N-STREAMING MFMA GEMM (MODE-0 / u-producing layers).
// Inverted loop nesting vs the m97-style kernel: the A-panel (MB=64 rows x
// K) is RESIDENT in LDS (loaded once); the loop runs over N in chunks of
// NC cols with double-buffered B-chunks and counted vmcnt (steady
// vmcnt(3), never 0).  Stores happen EVERY iteration, interleaved with
// stage-loads and MFMA -> continuous store stream per CU (duty-cycle
// probe; the old structure bursts all stores at block end).
// All LDS sub-tiles are [rows][32el] with the round-0 bank swizzle
// (measured 0 conflicts): 16B unit u holds col-block (u - (row>>1)) & 3,
// staged by permuting the per-lane GLOBAL source col (linear LDS dest,
// rule 21), read back with cls = ((lane>>4) + ((lane>>1)&3)) & 3.
// Per-wave VM ops/iter: stage nB copies + nS stores; at top of iter nc
// (nc>=1) ops newer than B(nc) = nB + nS = 3 for both K variants.
// K=64 : NC=32, NITER=24, wave = 16 rows x 32 cols (CT=2), LDS 16 KB.
// K=256: NC=16, NITER=48, wave = 16 rows x 16 cols (CT=1), LDS 48 KB.
// Output: u PANEL-MAJOR u5[col>>7][m>>2][col&127][m&3], +bias.
// -------------------------------------------------------------------------
template <int K>
__global__ __launch_bounds__(256) void gemm_nstream(
    const __hip_bfloat16* __restrict__ A, const __hip_bfloat16* __restrict__ Bt,
    const float* __restrict__ bias, __hip_bfloat16* __restrict__ out)
{
  constexpr int NT    = K / 32;              // k-steps
  constexpr int MB    = 64;                  // rows per block
  constexpr int NC    = (K == 64) ? 32 : 16; // cols per iteration
  constexpr int CT    = NC / 16;             // col-tiles per wave
  constexpr int NITER = 768 / NC;
  constexpr int ABUF  = NT * MB * 32;        // elements
  constexpr int BBUF  = NT * NC * 32;        // elements per buffer
  __shared__ __hip_bfloat16 lds[ABUF + 2 * BBUF];

  const int tid  = threadIdx.x;
  const int lane = tid & 63;
  const int wave = tid >> 6;
  const int m0   = blockIdx.x * MB;

  // staging lane map (round-0 pattern): row-in-chunk = lane>>2, swizzled
  // source col-block scb.
  const int srow = lane >> 2;
  const int scb  = ((lane & 3) - ((lane >> 3) & 3)) & 3;

  // ---- A resident: NT sub-buffers [MB][32]; copy ci = kt*(MB/16)+rc
  {
    constexpr int ACOPIES = NT * (MB / 16);  // K=64: 8, K=256: 32
    constexpr int PER_W   = ACOPIES / 4;
#pragma unroll
    for (int q = 0; q < PER_W; ++q) {
      const int ci = wave * PER_W + q;
      const int kt = ci / (MB / 16);
      const int rc = ci % (MB / 16);
      const int row = rc * 16 + srow;
      async_copy16((char*)lds + ci * 1024,
                   A + (size_t)(m0 + row) * K + kt * 32 + scb * 8);
    }
  }

  // ---- B chunk staging: NT sub-buffers [NC][32] per buffer
  auto stageB = [&](int nc, int buf) {
    constexpr int BCOPIES = NT * CT;         // K=64: 4, K=256: 8
    constexpr int PER_W   = BCOPIES / 4;     // 1 or 2
#pragma unroll
    for (int q = 0; q < PER_W; ++q) {
      const int ci = wave * PER_W + q;
      const int kt = ci / CT;
      const int cc = ci % CT;                // 16-col half
      const int s  = cc * 16 + srow;         // col within chunk
      async_copy16((char*)lds + (size_t)(ABUF + buf * BBUF) * 2 + ci * 1024,
                   Bt + (size_t)(nc * NC + s) * K + kt * 32 + scb * 8);
    }
  };

  stageB(0, 0);
  stageB(1, 1);

  const int rsel = lane & 15;
  const int cls  = ((lane >> 4) + ((lane >> 1) & 3)) & 3;
  const int wrow = wave * 16;                // wave's 16-row tile

  for (int nc = 0; nc < NITER; ++nc) {
    // Drain to B(nc) landed (A older -> retired too).  Steady state: ops
    // newer than B(nc) = stage(nB) + stores(nS) = 3.  Iter 0: only B1.
    if constexpr (K == 64) {
      if (nc == 0) { VM_WAIT(1); } else { VM_WAIT(3); }
    } else {
      if (nc == 0) { VM_WAIT(2); } else { VM_WAIT(3); }
    }
    __builtin_amdgcn_s_barrier();

    bf16x8 af[NT], bg[CT][NT];
    const __hip_bfloat16* bbase = lds + ABUF + (nc & 1) * BBUF;
#pragma unroll
    for (int kt = 0; kt < NT; ++kt) {
      af[kt] = *reinterpret_cast<const bf16x8*>(
          lds + kt * MB * 32 + (wrow + rsel) * 32 + cls * 8);
#pragma unroll
      for (int j = 0; j < CT; ++j)
        bg[j][kt] = *reinterpret_cast<const bf16x8*>(
            bbase + kt * NC * 32 + (j * 16 + rsel) * 32 + cls * 8);
    }
    LGKM_WAIT0;                          // frags in regs
    __builtin_amdgcn_sched_barrier(0);   // rule 18
    __builtin_amdgcn_s_barrier();        // all waves done reading buf nc&1

    // stage chunk nc+2 into the just-freed buffer; tail re-stages the
    // last chunk (never read) to keep the per-iter VM op count uniform.
    const int ncs = (nc + 2 < NITER) ? nc + 2 : NITER - 1;
    stageB(ncs, nc & 1);

    __builtin_amdgcn_s_setprio(1);
    f32x4 acc[CT] = {};
#pragma unroll
    for (int kt = 0; kt < NT; ++kt)
#pragma unroll
      for (int j = 0; j < CT; ++j)
        acc[j] = __builtin_amdgcn_mfma_f32_16x16x32_bf16(af[kt], bg[j][kt],
                                                         acc[j], 0, 0, 0);
    __builtin_amdgcn_s_setprio(0);

    // Distributed epilogue: CT stores of 8B per lane per iteration.
    // C/D layout: col = lane&15, row = (lane>>4)*4 + e  [verified m89]
    const int rowb = m0 + wrow + (lane >> 4) * 4;   // multiple of 4
#pragma unroll
    for (int j = 0; j < CT; ++j) {
      const int col = nc * NC + j * 16 + rsel;
      const float b = bias[col];
      bf16x4 v;
#pragma unroll
      for (int e = 0; e < 4; ++e)
        v[e] = (__bf16)(acc[j][e] + b);
      __hip_bfloat16* p = out +
          ((size_t)(col >> 7) * MG + (rowb >> 2)) * 512 + (col & 127) * 4;
      *reinterpret_cast<bf16x4*>(p) = v;
    }
  }
}

// -------------------------------------------------------------------------
// MFMA GEMM (round-9 structure) — used for the OUTPUT GEMM only (MODE 1).
// -------------------------------------------------------------------------
template <int K, int MODE>
__global__ __launch_bounds__(256) void gemm_mfma(
    const __hip_bfloat16* __restrict__ A, const __hip_bfloat16* __restrict__ Bt,
    const float* __restrict__ bias, void* __restrict__ out)
{
  constexpr int NT  = K / 32;
  constexpr int NBN = (MODE == 0) ? 6 : 1;
  __shared__ __hip_bfloat16 lds[16384];  // 32 KB: 2 bufs x (A 4096 + B 4096 el)
  const int tid  = threadIdx.x;
  const int lane = tid & 63;
  const int wave = tid >> 6;
  const int wm = wave >> 1, wn = wave & 1;

  const int bid  = blockIdx.x;
  const int xcd  = bid & 7;
  const int slot = bid >> 3;
  const int mg   = slot / NBN;
  const int nb   = slot - mg * NBN;
  const int m0   = (xcd * 64 + mg) * 128;
  const int n0   = nb * 128;

  const int srow = lane >> 2;
  const int scb  = ((lane & 3) - ((lane >> 3) & 3)) & 3;
  const int c0   = wave * 2;

  const __hip_bfloat16* gA = A + (size_t)(m0 + c0 * 16 + srow) * K + scb * 8;
  const __hip_bfloat16* gB = Bt + (size_t)(n0 + c0 * 16 + srow) * K + scb * 8;

  f32x4 acc[4][4] = {};

  const int rsel = lane & 15;
  const int cls  = ((lane >> 4) + ((lane >> 1) & 3)) & 3;

  auto stage = [&](int kt, int buf) {
    char* la = (char*)lds + buf * 16384 + c0 * 1024;
    const __hip_bfloat16* a = gA + kt * 32;
    async_copy16(la, a);
    async_copy16(la + 1024, a + 16 * K);
    char* lb = (char*)lds + buf * 16384 + 8192 + c0 * 1024;
    const __hip_bfloat16* b = gB + kt * 32;
    async_copy16(lb, b);
    async_copy16(lb + 1024, b + 16 * K);
  };

  stage(0, 0);
  stage(1, 1);

#pragma unroll
  for (int kt = 0; kt < NT; ++kt) {
    if (kt < NT - 1) { VM_WAIT(4); } else { VM_WAIT(0); }
    __builtin_amdgcn_s_barrier();

    const __hip_bfloat16* base = lds + (kt & 1) * 8192;
    bf16x8 af[4], bg[4];
#pragma unroll
    for (int i = 0; i < 4; ++i) {
      af[i] = *reinterpret_cast<const bf16x8*>(
          base + (wm * 64 + i * 16 + rsel) * 32 + cls * 8);
      bg[i] = *reinterpret_cast<const bf16x8*>(
          base + 4096 + (wn * 64 + i * 16 + rsel) * 32 + cls * 8);
    }
    LGKM_WAIT0;
    __builtin_amdgcn_sched_barrier(0);
    __builtin_amdgcn_s_barrier();

    if (kt + 2 < NT) stage(kt + 2, kt & 1);

    __builtin_amdgcn_s_setprio(1);
#pragma unroll
    for (int i = 0; i < 4; ++i)
#pragma unroll
      for (int j = 0; j < 4; ++j)
        acc[i][j] = __builtin_amdgcn_mfma_f32_16x16x32_bf16(af[i], bg[j],
                                                            acc[i][j], 0, 0, 0);
    __builtin_amdgcn_s_setprio(0);
  }

  const int rbase = m0 + wm * 64 + (lane >> 4) * 4;
  const int cbase = n0 + wn * 64 + (lane & 15);
#pragma unroll
  for (int i = 0; i < 4; ++i) {
#pragma unroll
    for (int j = 0; j < 4; ++j) {
      if (MODE == 0) {
        const int col = cbase + j * 16;
        const float b = bias[col];
        bf16x4 v;
#pragma unroll
        for (int e = 0; e < 4; ++e)
          v[e] = (__bf16)(acc[i][j][e] + b);
        __hip_bfloat16* p = (__hip_bfloat16*)out +
            ((size_t)(n0 >> 7) * MG + ((rbase + i * 16) >> 2)) * 512 +
            (col & 127) * 4;
        *reinterpret_cast<bf16x4*>(p) = v;
      } else {
#pragma unroll
        for (int e = 0; e < 4; ++e) {
          const int row = rbase + i * 16 + e;
          const int col = cbase + j * 16;
          if (col < 51) {
            ((float*)out)[(size_t)row * 51 + col] = acc[i][j][e] + bias[col];
          }
        }
      }
    }
  }
}

// -------------------------------------------------------------------------
// Chunked linear-recurrence scan over panel-major u (measured at BW roofline).
// u5[nb][m>>2][c][m&3]: col = gate*256 + h; nb = col>>7, c = col&127.
// sigmoid applied here (scans BW-bound, VALU idle).
// -------------------------------------------------------------------------
__global__ __launch_bounds__(256) void scan_p1(
    const __hip_bfloat16* __restrict__ u, float* __restrict__ Pa,
    float* __restrict__ Pb)
{
  const int blk = blockIdx.x;
  const int b = blk >> 5, ch = blk & 31;
  const int h = threadIdx.x;
  const int m4base = (b * 2048 + ch * TC) >> 2;
  const int cc = (h & 127) * 4;
  const __hip_bfloat16* px =
      u + ((size_t)(h >> 7) * MG + m4base) * 512 + cc;          // x_tilde
  const __hip_bfloat16* pf =
      u + ((size_t)(2 + (h >> 7)) * MG + m4base) * 512 + cc;    // f_pre
  float c = 0.f, a = 1.f;
#pragma unroll 4
  for (int t4 = 0; t4 < TC / 4; ++t4) {
    bf16x4 xv = *reinterpret_cast<const bf16x4*>(px + t4 * 512);
    bf16x4 fv = *reinterpret_cast<const bf16x4*>(pf + t4 * 512);
#pragma unroll
    for (int e = 0; e < 4; ++e) {
      float f  = sigmoid_f((float)fv[e]);
      float xt = (float)xv[e];
      c = f * c + (1.f - f) * xt;
      a *= f;
    }
  }
  const int o = (b * NCHUNK + ch) * 256 + h;
  Pa[o] = a;
  Pb[o] = c;
}

__global__ __launch_bounds__(256) void scan_p2(
    const float* __restrict__ Pa, const float* __restrict__ Pb,
    float* __restrict__ Cin)
{
  const int idx = blockIdx.x * 256 + threadIdx.x;  // 8192 = 32 b * 256 h
  const int b = idx >> 8, h = idx & 255;
  float c = 0.f;
  for (int ch = 0; ch < NCHUNK; ++ch) {
    const int o = (b * NCHUNK + ch) * 256 + h;
    Cin[o] = c;
    c = Pa[o] * c + Pb[o];
  }
}

__global__ __launch_bounds__(256) void scan_p3(
    const __hip_bfloat16* __restrict__ u, const float* __restrict__ Cin,
    __hip_bfloat16* __restrict__ hout)
{
  const int blk = blockIdx.x;
  const int b = blk >> 5, ch = blk & 31;
  const int h = threadIdx.x;
  const int m4base = (b * 2048 + ch * TC) >> 2;
  const int cc = (h & 127) * 4;
  const __hip_bfloat16* px =
      u + ((size_t)(h >> 7) * MG + m4base) * 512 + cc;
  const __hip_bfloat16* pf =
      u + ((size_t)(2 + (h >> 7)) * MG + m4base) * 512 + cc;
  const __hip_bfloat16* pr =
      u + ((size_t)(4 + (h >> 7)) * MG + m4base) * 512 + cc;
  __hip_bfloat16* ob = hout + (size_t)(b * 2048 + ch * TC) * 256;
  float c = Cin[(b * NCHUNK + ch) * 256 + h];
#pragma unroll 2
  for (int t4 = 0; t4 < TC / 4; ++t4) {
    bf16x4 xv = *reinterpret_cast<const bf16x4*>(px + t4 * 512);
    bf16x4 fv = *reinterpret_cast<const bf16x4*>(pf + t4 * 512);
    bf16x4 rv = *reinterpret_cast<const bf16x4*>(pr + t4 * 512);
#pragma unroll
    for (int e = 0; e < 4; ++e) {
      float xt = (float)xv[e];
      float f  = sigmoid_f((float)fv[e]);
      float r  = sigmoid_f((float)rv[e]);
      c = f * c + (1.f - f) * xt;
      float th = tanh_f(c);
      ob[(t4 * 4 + e) * 256 + h] = __float2bfloat16(r * th + (1.f - r) * xt);
    }
  }
}

// -------------------------------------------------------------------------
extern "C" void kernel_launch(void* const* d_in, const int* in_sizes, int n_in,
                              void* d_out, int out_size, void* d_ws, size_t ws_size,
                              hipStream_t stream) {
  const float* x     = (const float*)d_in[0];
  const float* W_in  = (const float*)d_in[1];
  const float* b_in  = (const float*)d_in[2];
  const float* W_l   = (const float*)d_in[3];
  const float* b_l   = (const float*)d_in[4];
  const float* W_out = (const float*)d_in[5];
  const float* b_out = (const float*)d_in[6];

  char* ws = (char*)d_ws;
  const size_t U_B    = (size_t)M_ROWS * 768 * 2;      // 100,663,296
  const size_t H_B    = (size_t)M_ROWS * 256 * 2;      //  33,554,432
  const size_t WT_B   = (size_t)2 * 768 * 256 * 2;     //     786,432
  const size_t WTO_B  = (size_t)128 * 256 * 2;         //      65,536
  const size_t WC_B   = (size_t)768 * 64 * 2;          //      98,304
  const size_t BC_B   = (size_t)768 * 4;               //       3,072
  const size_t XB_B   = (size_t)M_ROWS * 64 * 2;       //   8,388,608
  const size_t AB_B   = (size_t)32 * NCHUNK * 256 * 4; //   1,048,576

  size_t off = 0;
  __hip_bfloat16* u    = (__hip_bfloat16*)(ws + off); off += U_B;
  __hip_bfloat16* hA   = (__hip_bfloat16*)(ws + off); off += H_B;
  __hip_bfloat16* hB   = (__hip_bfloat16*)(ws + off); off += H_B;
  __hip_bfloat16* Wt   = (__hip_bfloat16*)(ws + off); off += WT_B;
  __hip_bfloat16* WtO  = (__hip_bfloat16*)(ws + off); off += WTO_B;
  __hip_bfloat16* WcT  = (__hip_bfloat16*)(ws + off); off += WC_B;
  float* bc  = (float*)(ws + off); off += BC_B;
  __hip_bfloat16* xb   = (__hip_bfloat16*)(ws + off); off += XB_B;
  float* Pa  = (float*)(ws + off); off += AB_B;
  float* Pb  = (float*)(ws + off); off += AB_B;
  float* Cin = (float*)(ws + off); off += AB_B;

  prep_weights<<<1860, 256, 0, stream>>>(W_l, W_out, W_in, b_in, b_l,
                                         Wt, WtO, WcT, bc);
  cast_x<<<M_ROWS * 8 / 256, 256, 0, stream>>>(x, xb);

  // layer 0: u = xb @ WcT^T + bc   (input GEMM folded in; K=64)
  gemm_nstream<64><<<M_ROWS / 64, 256, 0, stream>>>(xb, WcT, bc, u);
  scan_p1<<<32 * NCHUNK, 256, 0, stream>>>(u, Pa, Pb);
  scan_p2<<<32, 256, 0, stream>>>(Pa, Pb, Cin);
  scan_p3<<<32 * NCHUNK, 256, 0, stream>>>(u, Cin, hB);

  // layer 1
  gemm_nstream<256><<<M_ROWS / 64, 256, 0, stream>>>(hB, Wt + 768 * 256,
                                                     b_l + 768, u);
  scan_p1<<<32 * NCHUNK, 256, 0, stream>>>(u, Pa, Pb);
  scan_p2<<<32, 256, 0, stream>>>(Pa, Pb, Cin);
  scan_p3<<<32 * NCHUNK, 256, 0, stream>>>(u, Cin, hA);

  // output GEMM
  gemm_mfma<256, 1><<<M_ROWS / 128, 256, 0, stream>>>(hA, WtO, b_out, d_out);

  (void)in_sizes; (void)n_in; (void)out_size; (void)ws_size;
}

// Round 16
// 189.153 us; speedup vs baseline: 1.1361x; 1.1361x over previous
//
#include <hip/hip_runtime.h>
#include <hip/hip_bf16.h>

// x: [32, 2048, 17, 3] -> [65536, 51]
// u: panel-major packed bf16: u5[nb(0..5)][m>>2][c(0..127)][m&3], nb=col>>7
//    (PRE-activation f/r).  y: [65536, 51]
static constexpr int M_ROWS = 32 * 2048;   // 65536
static constexpr int MG     = M_ROWS / 4;  // 16384 m-groups
static constexpr int TC     = 64;          // scan chunk length
static constexpr int NCHUNK = 2048 / TC;   // 32

typedef __attribute__((ext_vector_type(8))) __bf16 bf16x8;
typedef __attribute__((ext_vector_type(4))) __bf16 bf16x4;
typedef __attribute__((ext_vector_type(4))) float  f32x4;

#define VM_WAIT(N) asm volatile("s_waitcnt vmcnt(" #N ")" ::: "memory")
#define LGKM_WAIT0 asm volatile("s_waitcnt lgkmcnt(0)" ::: "memory")

__device__ __forceinline__ void async_copy16(void* lds_ptr, const void* g_ptr) {
  __builtin_amdgcn_global_load_lds(
      (const __attribute__((address_space(1))) void*)g_ptr,
      (__attribute__((address_space(3))) void*)lds_ptr, 16, 0, 0);
}

__device__ __forceinline__ float sigmoid_f(float v) {
  return 1.f / (1.f + __expf(-v));
}
__device__ __forceinline__ float tanh_f(float v) {
  v = fminf(fmaxf(v, -15.f), 15.f);
  float e = __expf(-2.f * v);
  return (1.f - e) / (1.f + e);
}

// -------------------------------------------------------------------------
// Prep: W_l [2][256][768] f32 -> Wt [2][768][256] bf16 (transposed)
//       W_out [256][51] f32 -> WtO [128][256] bf16 (transposed, padded)
//       Wc = W_in @ W_l[0]  [51][768] f32-accum -> WcT [768][64] bf16
//       bc[o] = sum_j b_in[j]*W0[j][o] + b_l0[o]   (f32)
// -------------------------------------------------------------------------
__global__ __launch_bounds__(256) void prep_weights(
    const float* __restrict__ Wl, const float* __restrict__ Wout,
    const float* __restrict__ Win, const float* __restrict__ b_in,
    const float* __restrict__ b_l,
    __hip_bfloat16* __restrict__ Wt, __hip_bfloat16* __restrict__ WtO,
    __hip_bfloat16* __restrict__ WcT, float* __restrict__ bc)
{
  const int idx = blockIdx.x * 256 + threadIdx.x;
  const int T1 = 2 * 768 * 256;          // 393216
  const int T2 = T1 + 128 * 256;         // 425984
  const int T4 = T2 + 768 * 64;          // 475136
  const int T5 = T4 + 768;               // 475904
  if (idx < T1) {
    int l = idx / (768 * 256);
    int rem = idx - l * 768 * 256;
    int n = rem >> 8;
    int k = rem & 255;
    Wt[idx] = __float2bfloat16(Wl[(size_t)l * 196608 + (size_t)k * 768 + n]);
  } else if (idx < T2) {
    int i2 = idx - T1;
    int n = i2 >> 8, k = i2 & 255;
    float v = (n < 51) ? Wout[(size_t)k * 51 + n] : 0.f;
    WtO[i2] = __float2bfloat16(v);
  } else if (idx < T4) {
    int i4 = idx - T2;
    int o = i4 >> 6, k = i4 & 63;        // o: 0..767, k: 0..63
    float acc = 0.f;
    if (k < 51) {
      const float* wi = Win + (size_t)k * 256;   // row k of W_in, contiguous
      for (int j = 0; j < 256; ++j)
        acc += wi[j] * Wl[(size_t)j * 768 + o];  // W0 = W_l[0]
    }
    WcT[i4] = __float2bfloat16(acc);
  } else if (idx < T5) {
    int o = idx - T4;
    float acc = b_l[o];                  // b_l0
    for (int j = 0; j < 256; ++j)
      acc += b_in[j] * Wl[(size_t)j * 768 + o];
    bc[o] = acc;
  }
}

// -------------------------------------------------------------------------
// cast/pad x [65536][51] f32 -> xb [65536][64] bf16
// -------------------------------------------------------------------------
__global__ __launch_bounds__(256) void cast_x(
    const float* __restrict__ x, __hip_bfloat16* __restrict__ xb)
{
  const int t = blockIdx.x * 256 + threadIdx.x;  // 524288 = 65536 * 8
  const int row = t >> 3, cg = t & 7;
  __hip_bfloat16 tmp[8];
#pragma unroll
  for (int i = 0; i < 8; ++i) {
    int c = cg * 8 + i;
    float v = (c < 51) ? x[(size_t)row * 51 + c] : 0.f;
    tmp[i] = __float2bfloat16(v);
  }
  *reinterpret_cast<int4*>(&xb[(size_t)row * 64 + cg * 8]) =
      *reinterpret_cast<const int4*>(tmp);
}

// -------------------------------------------------------------------------
// MFMA GEMM, 128x128 tile, 4 waves (2x2), 16x16x32 bf16, K templated.
// A: [M][K] bf16 row-major.  Bt: [N][K] bf16 (pre-transposed weights).
// Grid: 1-D, XCD-chunked (T1).  LDS: double-buffered 32 KB, depth-2
// prefetch, counted vmcnt, raw barriers; round-0 bank swizzle (0 conflicts).
// MODE 0: out = u PANEL-MAJOR u5[nb][m>>2][c][m&3] (nb = n0>>7), +bias.
// MODE 1: out = y f32 [M][51] row-major, +bias, cols < 51.  NBN=1.
// Final configuration (15-round ledger): every execution-side lever on this
// GEMM measured-refuted (stores, sync, locality, tile, occupancy,
// persistence, fusion, duty-cycle); scans at BW roofline.  Best measured
// decomposition: 189.7-190.6 us across four benches.
// -------------------------------------------------------------------------
template <int K, int MODE>
__global__ __launch_bounds__(256) void gemm_mfma(
    const __hip_bfloat16* __restrict__ A, const __hip_bfloat16* __restrict__ Bt,
    const float* __restrict__ bias, void* __restrict__ out)
{
  constexpr int NT  = K / 32;
  constexpr int NBN = (MODE == 0) ? 6 : 1;
  __shared__ __hip_bfloat16 lds[16384];  // 32 KB: 2 bufs x (A 4096 + B 4096 el)
  const int tid  = threadIdx.x;
  const int lane = tid & 63;
  const int wave = tid >> 6;
  const int wm = wave >> 1, wn = wave & 1;

  // XCD-chunked block swizzle (T1); bijective: grid % 8 == 0
  const int bid  = blockIdx.x;
  const int xcd  = bid & 7;
  const int slot = bid >> 3;            // 64*NBN slots per XCD
  const int mg   = slot / NBN;
  const int nb   = slot - mg * NBN;
  const int m0   = (xcd * 64 + mg) * 128;
  const int n0   = nb * 128;

  // staging: lane -> (row = lane>>2, swizzled source col-block)
  const int srow = lane >> 2;
  const int scb  = ((lane & 3) - ((lane >> 3) & 3)) & 3;
  const int c0   = wave * 2;  // this wave stages 16-row chunks c0, c0+1 of A and B

  const __hip_bfloat16* gA = A + (size_t)(m0 + c0 * 16 + srow) * K + scb * 8;
  const __hip_bfloat16* gB = Bt + (size_t)(n0 + c0 * 16 + srow) * K + scb * 8;

  f32x4 acc[4][4] = {};

  const int rsel = lane & 15;
  const int cls  = ((lane >> 4) + ((lane >> 1) & 3)) & 3;  // read-side swizzle class

  auto stage = [&](int kt, int buf) {
    char* la = (char*)lds + buf * 16384 + c0 * 1024;
    const __hip_bfloat16* a = gA + kt * 32;
    async_copy16(la, a);
    async_copy16(la + 1024, a + 16 * K);
    char* lb = (char*)lds + buf * 16384 + 8192 + c0 * 1024;
    const __hip_bfloat16* b = gB + kt * 32;
    async_copy16(lb, b);
    async_copy16(lb + 1024, b + 16 * K);
  };

  stage(0, 0);
  stage(1, 1);

#pragma unroll
  for (int kt = 0; kt < NT; ++kt) {
    // Outstanding here: tiles kt, kt+1 (8 loads).  Drain to tile kt landed.
    if (kt < NT - 1) { VM_WAIT(4); } else { VM_WAIT(0); }
    __builtin_amdgcn_s_barrier();

    const __hip_bfloat16* base = lds + (kt & 1) * 8192;
    bf16x8 af[4], bg[4];
#pragma unroll
    for (int i = 0; i < 4; ++i) {
      af[i] = *reinterpret_cast<const bf16x8*>(
          base + (wm * 64 + i * 16 + rsel) * 32 + cls * 8);
      bg[i] = *reinterpret_cast<const bf16x8*>(
          base + 4096 + (wn * 64 + i * 16 + rsel) * 32 + cls * 8);
    }
    LGKM_WAIT0;                          // frags in regs
    __builtin_amdgcn_sched_barrier(0);   // rule 18
    __builtin_amdgcn_s_barrier();        // all waves done reading buf kt&1

    if (kt + 2 < NT) stage(kt + 2, kt & 1);  // just-freed buffer

    __builtin_amdgcn_s_setprio(1);
#pragma unroll
    for (int i = 0; i < 4; ++i)
#pragma unroll
      for (int j = 0; j < 4; ++j)
        acc[i][j] = __builtin_amdgcn_mfma_f32_16x16x32_bf16(af[i], bg[j],
                                                            acc[i][j], 0, 0, 0);
    __builtin_amdgcn_s_setprio(0);
  }

  // Epilogue.  C/D layout: col = lane&15, row = (lane>>4)*4 + e  [verified m89]
  const int rbase = m0 + wm * 64 + (lane >> 4) * 4;   // multiple of 4
  const int cbase = n0 + wn * 64 + (lane & 15);
#pragma unroll
  for (int i = 0; i < 4; ++i) {
#pragma unroll
    for (int j = 0; j < 4; ++j) {
      if (MODE == 0) {
        const int col = cbase + j * 16;
        const float b = bias[col];
        bf16x4 v;
#pragma unroll
        for (int e = 0; e < 4; ++e)
          v[e] = (__bf16)(acc[i][j][e] + b);
        // u5[nb][m>>2][c][e]: nb = n0>>7 (block-const), c = col&127
        __hip_bfloat16* p = (__hip_bfloat16*)out +
            ((size_t)(n0 >> 7) * MG + ((rbase + i * 16) >> 2)) * 512 +
            (col & 127) * 4;
        *reinterpret_cast<bf16x4*>(p) = v;
      } else {
#pragma unroll
        for (int e = 0; e < 4; ++e) {
          const int row = rbase + i * 16 + e;
          const int col = cbase + j * 16;
          if (col < 51) {
            ((float*)out)[(size_t)row * 51 + col] = acc[i][j][e] + bias[col];
          }
        }
      }
    }
  }
}

// -------------------------------------------------------------------------
// Chunked linear-recurrence scan over panel-major u (measured at BW roofline).
// u5[nb][m>>2][c][m&3]: col = gate*256 + h; nb = col>>7, c = col&127.
// sigmoid applied here (scans BW-bound, VALU idle).
// -------------------------------------------------------------------------
__global__ __launch_bounds__(256) void scan_p1(
    const __hip_bfloat16* __restrict__ u, float* __restrict__ Pa,
    float* __restrict__ Pb)
{
  const int blk = blockIdx.x;
  const int b = blk >> 5, ch = blk & 31;
  const int h = threadIdx.x;
  const int m4base = (b * 2048 + ch * TC) >> 2;
  const int cc = (h & 127) * 4;
  const __hip_bfloat16* px =
      u + ((size_t)(h >> 7) * MG + m4base) * 512 + cc;          // x_tilde
  const __hip_bfloat16* pf =
      u + ((size_t)(2 + (h >> 7)) * MG + m4base) * 512 + cc;    // f_pre
  float c = 0.f, a = 1.f;
#pragma unroll 4
  for (int t4 = 0; t4 < TC / 4; ++t4) {
    bf16x4 xv = *reinterpret_cast<const bf16x4*>(px + t4 * 512);
    bf16x4 fv = *reinterpret_cast<const bf16x4*>(pf + t4 * 512);
#pragma unroll
    for (int e = 0; e < 4; ++e) {
      float f  = sigmoid_f((float)fv[e]);
      float xt = (float)xv[e];
      c = f * c + (1.f - f) * xt;
      a *= f;
    }
  }
  const int o = (b * NCHUNK + ch) * 256 + h;
  Pa[o] = a;
  Pb[o] = c;
}

__global__ __launch_bounds__(256) void scan_p2(
    const float* __restrict__ Pa, const float* __restrict__ Pb,
    float* __restrict__ Cin)
{
  const int idx = blockIdx.x * 256 + threadIdx.x;  // 8192 = 32 b * 256 h
  const int b = idx >> 8, h = idx & 255;
  float c = 0.f;
  for (int ch = 0; ch < NCHUNK; ++ch) {
    const int o = (b * NCHUNK + ch) * 256 + h;
    Cin[o] = c;
    c = Pa[o] * c + Pb[o];
  }
}

__global__ __launch_bounds__(256) void scan_p3(
    const __hip_bfloat16* __restrict__ u, const float* __restrict__ Cin,
    __hip_bfloat16* __restrict__ hout)
{
  const int blk = blockIdx.x;
  const int b = blk >> 5, ch = blk & 31;
  const int h = threadIdx.x;
  const int m4base = (b * 2048 + ch * TC) >> 2;
  const int cc = (h & 127) * 4;
  const __hip_bfloat16* px =
      u + ((size_t)(h >> 7) * MG + m4base) * 512 + cc;
  const __hip_bfloat16* pf =
      u + ((size_t)(2 + (h >> 7)) * MG + m4base) * 512 + cc;
  const __hip_bfloat16* pr =
      u + ((size_t)(4 + (h >> 7)) * MG + m4base) * 512 + cc;
  __hip_bfloat16* ob = hout + (size_t)(b * 2048 + ch * TC) * 256;
  float c = Cin[(b * NCHUNK + ch) * 256 + h];
#pragma unroll 2
  for (int t4 = 0; t4 < TC / 4; ++t4) {
    bf16x4 xv = *reinterpret_cast<const bf16x4*>(px + t4 * 512);
    bf16x4 fv = *reinterpret_cast<const bf16x4*>(pf + t4 * 512);
    bf16x4 rv = *reinterpret_cast<const bf16x4*>(pr + t4 * 512);
#pragma unroll
    for (int e = 0; e < 4; ++e) {
      float xt = (float)xv[e];
      float f  = sigmoid_f((float)fv[e]);
      float r  = sigmoid_f((float)rv[e]);
      c = f * c + (1.f - f) * xt;
      float th = tanh_f(c);
      ob[(t4 * 4 + e) * 256 + h] = __float2bfloat16(r * th + (1.f - r) * xt);
    }
  }
}

// -------------------------------------------------------------------------
extern "C" void kernel_launch(void* const* d_in, const int* in_sizes, int n_in,
                              void* d_out, int out_size, void* d_ws, size_t ws_size,
                              hipStream_t stream) {
  const float* x     = (const float*)d_in[0];
  const float* W_in  = (const float*)d_in[1];
  const float* b_in  = (const float*)d_in[2];
  const float* W_l   = (const float*)d_in[3];
  const float* b_l   = (const float*)d_in[4];
  const float* W_out = (const float*)d_in[5];
  const float* b_out = (const float*)d_in[6];

  char* ws = (char*)d_ws;
  const size_t U_B    = (size_t)M_ROWS * 768 * 2;      // 100,663,296
  const size_t H_B    = (size_t)M_ROWS * 256 * 2;      //  33,554,432
  const size_t WT_B   = (size_t)2 * 768 * 256 * 2;     //     786,432
  const size_t WTO_B  = (size_t)128 * 256 * 2;         //      65,536
  const size_t WC_B   = (size_t)768 * 64 * 2;          //      98,304
  const size_t BC_B   = (size_t)768 * 4;               //       3,072
  const size_t XB_B   = (size_t)M_ROWS * 64 * 2;       //   8,388,608
  const size_t AB_B   = (size_t)32 * NCHUNK * 256 * 4; //   1,048,576

  size_t off = 0;
  __hip_bfloat16* u    = (__hip_bfloat16*)(ws + off); off += U_B;
  __hip_bfloat16* hA   = (__hip_bfloat16*)(ws + off); off += H_B;
  __hip_bfloat16* hB   = (__hip_bfloat16*)(ws + off); off += H_B;
  __hip_bfloat16* Wt   = (__hip_bfloat16*)(ws + off); off += WT_B;
  __hip_bfloat16* WtO  = (__hip_bfloat16*)(ws + off); off += WTO_B;
  __hip_bfloat16* WcT  = (__hip_bfloat16*)(ws + off); off += WC_B;
  float* bc  = (float*)(ws + off); off += BC_B;
  __hip_bfloat16* xb   = (__hip_bfloat16*)(ws + off); off += XB_B;
  float* Pa  = (float*)(ws + off); off += AB_B;
  float* Pb  = (float*)(ws + off); off += AB_B;
  float* Cin = (float*)(ws + off); off += AB_B;

  prep_weights<<<1860, 256, 0, stream>>>(W_l, W_out, W_in, b_in, b_l,
                                         Wt, WtO, WcT, bc);
  cast_x<<<M_ROWS * 8 / 256, 256, 0, stream>>>(x, xb);

  // layer 0: u = xb @ WcT^T + bc   (input GEMM folded in; K=64)
  gemm_mfma<64, 0><<<M_ROWS / 128 * 6, 256, 0, stream>>>(xb, WcT, bc, u);
  scan_p1<<<32 * NCHUNK, 256, 0, stream>>>(u, Pa, Pb);
  scan_p2<<<32, 256, 0, stream>>>(Pa, Pb, Cin);
  scan_p3<<<32 * NCHUNK, 256, 0, stream>>>(u, Cin, hB);

  // layer 1
  gemm_mfma<256, 0><<<M_ROWS / 128 * 6, 256, 0, stream>>>(hB, Wt + 768 * 256,
                                                          b_l + 768, u);
  scan_p1<<<32 * NCHUNK, 256, 0, stream>>>(u, Pa, Pb);
  scan_p2<<<32, 256, 0, stream>>>(Pa, Pb, Cin);
  scan_p3<<<32 * NCHUNK, 256, 0, stream>>>(u, Cin, hA);

  // output GEMM
  gemm_mfma<256, 1><<<M_ROWS / 128, 256, 0, stream>>>(hA, WtO, b_out, d_out);

  (void)in_sizes; (void)n_in; (void)out_size; (void)ws_size;
}